// Round 6
// baseline (23.776 us; speedup 1.0000x reference)
//
#include <hip/hip_runtime.h>

// HardUpsampling: seqs [N=16, T=2048, M=256] f32, durations [N, T] i32 in [0,4)
// out = concat( upsampled [N, L, M] f32 , lens [N] (written as f32) )
//
// Round 6: kill the cum-array dependency chain.
//  - k1 shrunk to a 4KB group-prefix table (16 rows x 64 groups of 32 tokens):
//    16 single-wave blocks, 8 int4 loads + 6-shfl scan + 4B store/lane.
//  - k2 issues its 4 big row loads FIRST (unconditional, independent of all
//    scalar state), then reconstructs offsets from gp[g] (4KB, L2-hot) + one
//    128B coalesced durations load (L1-hot, shared by 8 waves) + 5-shfl scan.
//    No 128KB cum write, no per-wave HBM-latency boundary loads on the
//    critical path.

#define N_ROWS 16
#define T_LEN  2048
#define M_DIM  256
#define M_VEC  (M_DIM / 4)   // 64 float4 per row
#define W_TOK  4             // tokens per wave
#define GRP    32            // tokens per prefix group (64 groups/row)

typedef float f32x4 __attribute__((ext_vector_type(4)));

// ---------------- Kernel 1: per-row group prefixes + lens ----------------
// grid = N_ROWS blocks, block = 64. Lane l owns tokens [l*32, l*32+32).
__global__ __launch_bounds__(64) void pregroup_kernel(
    const int* __restrict__ dur, int* __restrict__ gp,
    int* __restrict__ lens_i, float* __restrict__ lens_out) {
  const int n = blockIdx.x;
  const int lane = threadIdx.x;
  const int base = n * T_LEN + lane * GRP;

  int tot = 0;
#pragma unroll
  for (int j = 0; j < GRP / 4; ++j) {
    const int4 v = *(const int4*)(dur + base + j * 4);
    tot += v.x + v.y + v.z + v.w;
  }

  int scan = tot;                          // inclusive scan of group sums
#pragma unroll
  for (int d = 1; d < 64; d <<= 1) {
    const int t = __shfl_up(scan, d, 64);
    if (lane >= d) scan += t;
  }

  gp[(n << 6) + lane] = scan - tot;        // exclusive prefix of group `lane`
  if (lane == 63) {
    lens_i[n] = scan;                      // row total
    lens_out[n] = (float)scan;
  }
}

// ---------------- Kernel 2: scatter + pad ----------------
// One wave per 4 consecutive indices [p, p+4). 4 waves / 256-thr block.
__global__ __launch_bounds__(256) void scatter_kernel(
    const f32x4* __restrict__ seqs4, const int* __restrict__ dur,
    const int* __restrict__ gp, const int* __restrict__ lens_i,
    f32x4* __restrict__ out4, int max_len) {
  const int lane = threadIdx.x & 63;
  const int wave = threadIdx.x >> 6;
  const int n = blockIdx.y;
  const int p = (blockIdx.x * 4 + wave) * W_TOK;
  const bool tok = (p < T_LEN);            // wave-uniform

  const f32x4* __restrict__ srow = seqs4 + (size_t)n * T_LEN * M_VEC + lane;
  f32x4* __restrict__ orow = out4 + (size_t)n * max_len * M_VEC + lane;

  // ---- issue the 4 big row loads first; nothing scalar gates them ----
  f32x4 v[W_TOK];
#pragma unroll
  for (int k = 0; k < W_TOK; ++k) {
    v[k] = (f32x4)0.f;
    if (tok) v[k] = srow[(size_t)(p + k) * M_VEC];
  }

  const int len = lens_i[n];               // wave-uniform, L2-hot (64B array)

  if (tok) {
    const int g = p >> 5;                  // 32-token group
    const int q = p & 31;                  // offset inside group
    // lanes 0..31: this group's 32 durations (128B coalesced, L1-hot)
    int dl = (lane < GRP) ? dur[n * T_LEN + (g << 5) + lane] : 0;
    int sc = dl;                           // inclusive scan over lanes 0..31
#pragma unroll
    for (int d = 1; d < GRP; d <<= 1) {
      const int t = __shfl_up(sc, d, 64);
      if (lane >= d) sc += t;
    }
    const int base_gp = gp[(n << 6) + g];  // 4KB table, L2-hot

    int st[W_TOK], dk[W_TOK];
#pragma unroll
    for (int k = 0; k < W_TOK; ++k) {
      const int j = q + k;
      const int incl_prev = (j == 0) ? 0 : __shfl(sc, j - 1, 64);
      st[k] = base_gp + incl_prev;         // exclusive prefix at token p+k
      dk[k] = __shfl(dl, j, 64);           // duration of token p+k (0..3)
    }

    // scatter: d<=3 -> 3 predicated stores per token
#pragma unroll
    for (int k = 0; k < W_TOK; ++k) {
      if (dk[k] > 0) orow[(size_t)(st[k] + 0) * M_VEC] = v[k];
      if (dk[k] > 1) orow[(size_t)(st[k] + 1) * M_VEC] = v[k];
      if (dk[k] > 2) orow[(size_t)(st[k] + 2) * M_VEC] = v[k];
    }
  }

  // ---- padding: output rows [len, max_len) in this wave's range ----
  const f32x4 z = (f32x4)0.f;
#pragma unroll
  for (int k = 0; k < W_TOK; ++k) {
    const int i = p + k;
    if (i >= len && i < max_len) orow[(size_t)i * M_VEC] = z;
  }
}

extern "C" void kernel_launch(void* const* d_in, const int* in_sizes, int n_in,
                              void* d_out, int out_size, void* d_ws, size_t ws_size,
                              hipStream_t stream) {
  const float* seqs = (const float*)d_in[0];       // [16, 2048, 256] f32
  const int* durations = (const int*)d_in[1];      // [16, 2048] i32
  float* out = (float*)d_out;

  const int N = N_ROWS;
  const int M = M_DIM;
  const int max_len = (out_size - N) / (N * M);    // padded output length L

  int* gp = (int*)d_ws;                            // 16*64 ints = 4KB
  int* lens_i = gp + N_ROWS * 64;                  // 16 ints
  float* lens_out = out + (size_t)N * max_len * M; // lens chunk (as f32 values)

  pregroup_kernel<<<dim3(N), dim3(64), 0, stream>>>(
      durations, gp, lens_i, lens_out);

  const int span = (max_len > T_LEN) ? max_len : T_LEN;
  dim3 grid((span + 4 * W_TOK - 1) / (4 * W_TOK), N);
  scatter_kernel<<<grid, dim3(256), 0, stream>>>(
      (const f32x4*)seqs, durations, gp, lens_i, (f32x4*)out, max_len);
}

// Round 7
// 19.544 us; speedup vs baseline: 1.2166x; 1.2166x over previous
//
#include <hip/hip_runtime.h>

// HardUpsampling: seqs [N=16, T=2048, M=256] f32, durations [N, T] i32 in [0,4)
// out = concat( upsampled [N, L, M] f32 , lens [N] (written as f32) )
//
// Round 7: SINGLE fused kernel (test launch-overhead hypothesis).
//  - Per BLOCK (not per wave - R3's mistake): full-row cumsum into LDS.
//    256 threads x 8 durations (2x int4, L2-hot) -> wave scans + LDS combine
//    -> cum[2048] in LDS. ~25 MB aggregate L2 reads, <1us.
//  - Big seqs row loads issued BEFORE the scan (independent) so HBM latency
//    hides under the prefix work.
//  - Each of 4 waves owns 4 positions: boundaries from LDS (broadcast reads),
//    d in [0,3] -> 3 predicated stores/token; pad rows [len, max_len) zeroed.

#define N_ROWS 16
#define T_LEN  2048
#define M_DIM  256
#define M_VEC  (M_DIM / 4)   // 64 float4 per row
#define W_TOK  4             // positions per wave
#define BLK_POS 16           // positions per block (4 waves x 4)

typedef float f32x4 __attribute__((ext_vector_type(4)));

__global__ __launch_bounds__(256) void fused_upsample_kernel(
    const f32x4* __restrict__ seqs4, const int* __restrict__ dur,
    f32x4* __restrict__ out4, float* __restrict__ lens_out, int max_len) {
  const int tid = threadIdx.x;
  const int lane = tid & 63;
  const int wave = tid >> 6;
  const int n = blockIdx.y;
  const int p = blockIdx.x * BLK_POS + wave * W_TOK;
  const bool tok = (p < T_LEN);            // wave-uniform

  const f32x4* __restrict__ srow = seqs4 + (size_t)n * T_LEN * M_VEC + lane;
  f32x4* __restrict__ orow = out4 + (size_t)n * max_len * M_VEC + lane;

  // ---- issue the 4 big row loads first; independent of all scalar state ----
  f32x4 v[W_TOK];
#pragma unroll
  for (int k = 0; k < W_TOK; ++k) {
    v[k] = (f32x4)0.f;
    if (tok) v[k] = srow[(size_t)(p + k) * M_VEC];
  }

  // ---- block-wide cumsum of this row into LDS (once per block) ----
  __shared__ int cums[T_LEN];              // 8 KB
  __shared__ int wtot[4];
  const int base = n * T_LEN + tid * 8;
  int4 a = *(const int4*)(dur + base);
  int4 b = *(const int4*)(dur + base + 4);
  int tot = 0;
  a.x = (tot += a.x); a.y = (tot += a.y); a.z = (tot += a.z); a.w = (tot += a.w);
  b.x = (tot += b.x); b.y = (tot += b.y); b.z = (tot += b.z); b.w = (tot += b.w);

  int scan = tot;                          // wave-inclusive scan of totals
#pragma unroll
  for (int d = 1; d < 64; d <<= 1) {
    const int t = __shfl_up(scan, d, 64);
    if (lane >= d) scan += t;
  }
  if (lane == 63) wtot[wave] = scan;
  __syncthreads();
  int woff = 0;
#pragma unroll
  for (int w = 0; w < 3; ++w) woff += (w < wave) ? wtot[w] : 0;

  const int excl = woff + scan - tot;
  a.x += excl; a.y += excl; a.z += excl; a.w += excl;
  b.x += excl; b.y += excl; b.z += excl; b.w += excl;
  *(int4*)(cums + tid * 8) = a;
  *(int4*)(cums + tid * 8 + 4) = b;
  __syncthreads();

  const int len = cums[T_LEN - 1];         // broadcast LDS read

  if (blockIdx.x == 0 && tid == 0) lens_out[n] = (float)len;

  // ---- scatter ----
  if (tok) {
    int st[W_TOK], dk[W_TOK];
#pragma unroll
    for (int k = 0; k < W_TOK; ++k) {
      const int c0 = (p + k == 0) ? 0 : cums[p + k - 1];  // broadcast reads
      const int c1 = cums[p + k];
      st[k] = c0;
      dk[k] = c1 - c0;                     // 0..3
    }
#pragma unroll
    for (int k = 0; k < W_TOK; ++k) {
      if (dk[k] > 0) orow[(size_t)(st[k] + 0) * M_VEC] = v[k];
      if (dk[k] > 1) orow[(size_t)(st[k] + 1) * M_VEC] = v[k];
      if (dk[k] > 2) orow[(size_t)(st[k] + 2) * M_VEC] = v[k];
    }
  }

  // ---- padding: output rows [len, max_len) in this wave's range ----
  const f32x4 z = (f32x4)0.f;
#pragma unroll
  for (int k = 0; k < W_TOK; ++k) {
    const int i = p + k;
    if (i >= len && i < max_len) orow[(size_t)i * M_VEC] = z;
  }
}

extern "C" void kernel_launch(void* const* d_in, const int* in_sizes, int n_in,
                              void* d_out, int out_size, void* d_ws, size_t ws_size,
                              hipStream_t stream) {
  const float* seqs = (const float*)d_in[0];       // [16, 2048, 256] f32
  const int* durations = (const int*)d_in[1];      // [16, 2048] i32
  float* out = (float*)d_out;

  const int N = N_ROWS;
  const int M = M_DIM;
  const int max_len = (out_size - N) / (N * M);    // padded output length L

  float* lens_out = out + (size_t)N * max_len * M; // lens chunk (as f32 values)

  const int span = (max_len > T_LEN) ? max_len : T_LEN;
  dim3 grid((span + BLK_POS - 1) / BLK_POS, N);
  fused_upsample_kernel<<<grid, dim3(256), 0, stream>>>(
      (const f32x4*)seqs, durations, (f32x4*)out, lens_out, max_len);
}